// Round 2
// baseline (1981.714 us; speedup 1.0000x reference)
//
#include <hip/hip_runtime.h>

#define NNODES 100000
#define NEDGES 1600000
#define HDIM 128
#define EDIM 32
#define SDIM 160          // HDIM + EDIM
#define KTOT 288          // HDIM + SDIM (node GEMM inner dim)
#define NT 16             // nodes per block in node kernel

// ---------------------------------------------------------------------------
// Kernel 1: per-edge scatter-add of raw payload [x[src] | edge_attr[e]] into
// S[dst] (160 f32 per node) plus degree count. One wave (64 lanes) per edge.
// ---------------------------------------------------------------------------
__global__ __launch_bounds__(256) void edge_scatter(
    const float* __restrict__ x,
    const int*   __restrict__ ei,    // [2, NEDGES]
    const float* __restrict__ ea,    // [NEDGES, EDIM]
    float*       __restrict__ S,     // [NNODES, SDIM]
    float*       __restrict__ deg)   // [NNODES]
{
    const int lane   = threadIdx.x & 63;
    const int wave   = (blockIdx.x * blockDim.x + threadIdx.x) >> 6;
    const int nwaves = (gridDim.x * blockDim.x) >> 6;

    for (int e = wave; e < NEDGES; e += nwaves) {
        const int src = ei[e];
        const int dst = ei[NEDGES + e];

        // coalesced 512B read of the source row: lane reads floats [2l, 2l+1]
        const float2 xv =
            *reinterpret_cast<const float2*>(x + (size_t)src * HDIM + 2 * lane);

        float* Sd = S + (size_t)dst * SDIM;
        atomicAdd(Sd + 2 * lane,     xv.x);
        atomicAdd(Sd + 2 * lane + 1, xv.y);

        if (lane < EDIM) {
            atomicAdd(Sd + HDIM + lane, ea[(size_t)e * EDIM + lane]);
        }
        if (lane == 0) {
            atomicAdd(deg + dst, 1.0f);
        }
    }
}

// ---------------------------------------------------------------------------
// Kernel 2: node update. out[n] = relu(x[n]@W_self + S[n]@W_msg
//                                      + b_self + deg[n]*b_msg)
// Block = 256 threads handles NT=16 nodes. Thread t: col c = t&127,
// node-group g = t>>7 (8 nodes each). float4 LDS broadcast reads, 8 acc.
// ---------------------------------------------------------------------------
__global__ __launch_bounds__(256) void node_update(
    const float* __restrict__ x,
    const float* __restrict__ S,
    const float* __restrict__ deg,
    const float* __restrict__ Wself,  // [HDIM, HDIM]
    const float* __restrict__ bself,  // [HDIM]
    const float* __restrict__ Wmsg,   // [SDIM, HDIM]
    const float* __restrict__ bmsg,   // [HDIM]
    float*       __restrict__ out)    // [NNODES, HDIM]
{
    __shared__ float in_tile[NT][KTOT];   // [n][0:128]=x row, [n][128:288]=S row
    __shared__ float deg_tile[NT];

    const int node0 = blockIdx.x * NT;

    // stage 16 node rows (x then S) into LDS
    for (int idx = threadIdx.x; idx < NT * KTOT; idx += 256) {
        const int n = idx / KTOT;
        const int k = idx - n * KTOT;
        float v;
        if (k < HDIM) v = x[(size_t)(node0 + n) * HDIM + k];
        else          v = S[(size_t)(node0 + n) * SDIM + (k - HDIM)];
        in_tile[n][k] = v;
    }
    if (threadIdx.x < NT) deg_tile[threadIdx.x] = deg[node0 + threadIdx.x];
    __syncthreads();

    const int c = threadIdx.x & (HDIM - 1);
    const int g = threadIdx.x >> 7;          // 0 or 1 -> nodes g*8 .. g*8+7

    float acc[8] = {0.f, 0.f, 0.f, 0.f, 0.f, 0.f, 0.f, 0.f};

    // x part: k = 0..127 against W_self
    for (int k = 0; k < HDIM; k += 4) {
        const float w0 = Wself[(k + 0) * HDIM + c];
        const float w1 = Wself[(k + 1) * HDIM + c];
        const float w2 = Wself[(k + 2) * HDIM + c];
        const float w3 = Wself[(k + 3) * HDIM + c];
        #pragma unroll
        for (int i = 0; i < 8; ++i) {
            const float4 v =
                *reinterpret_cast<const float4*>(&in_tile[g * 8 + i][k]);
            acc[i] += v.x * w0 + v.y * w1 + v.z * w2 + v.w * w3;
        }
    }
    // S part: k = 0..159 against W_msg
    for (int k = 0; k < SDIM; k += 4) {
        const float w0 = Wmsg[(k + 0) * HDIM + c];
        const float w1 = Wmsg[(k + 1) * HDIM + c];
        const float w2 = Wmsg[(k + 2) * HDIM + c];
        const float w3 = Wmsg[(k + 3) * HDIM + c];
        #pragma unroll
        for (int i = 0; i < 8; ++i) {
            const float4 v =
                *reinterpret_cast<const float4*>(&in_tile[g * 8 + i][HDIM + k]);
            acc[i] += v.x * w0 + v.y * w1 + v.z * w2 + v.w * w3;
        }
    }

    const float bs = bself[c];
    const float bm = bmsg[c];
    #pragma unroll
    for (int i = 0; i < 8; ++i) {
        const int n = g * 8 + i;
        const float h = acc[i] + bs + deg_tile[n] * bm;
        out[(size_t)(node0 + n) * HDIM + c] = fmaxf(h, 0.f);
    }
}

// ---------------------------------------------------------------------------
extern "C" void kernel_launch(void* const* d_in, const int* in_sizes, int n_in,
                              void* d_out, int out_size, void* d_ws, size_t ws_size,
                              hipStream_t stream)
{
    const float* x     = (const float*)d_in[0];
    const int*   ei    = (const int*)  d_in[1];
    const float* ea    = (const float*)d_in[2];
    const float* Wself = (const float*)d_in[3];
    const float* bself = (const float*)d_in[4];
    const float* Wmsg  = (const float*)d_in[5];
    const float* bmsg  = (const float*)d_in[6];
    float* out = (float*)d_out;

    float* S   = (float*)d_ws;                        // [NNODES, SDIM]
    float* deg = S + (size_t)NNODES * SDIM;           // [NNODES]

    const size_t zero_bytes = ((size_t)NNODES * SDIM + NNODES) * sizeof(float);
    hipMemsetAsync(d_ws, 0, zero_bytes, stream);

    edge_scatter<<<2048, 256, 0, stream>>>(x, ei, ea, S, deg);

    node_update<<<NNODES / NT, 256, 0, stream>>>(x, S, deg, Wself, bself,
                                                 Wmsg, bmsg, out);
}

// Round 4
// 1136.216 us; speedup vs baseline: 1.7441x; 1.7441x over previous
//
#include <hip/hip_runtime.h>

#define NNODES 100000
#define NEDGES 1600000
#define HDIM 128
#define EDIM 32
#define SDIM 160          // HDIM + EDIM
#define KTOT 288          // HDIM + SDIM (node GEMM inner dim)
#define NT2 64            // nodes per block in node kernel

// ---------------------------------------------------------------------------
// CSR build kernel 1: histogram of dst degrees.
// ---------------------------------------------------------------------------
__global__ __launch_bounds__(256) void hist_kernel(
    const int* __restrict__ ei, int* __restrict__ cnt)
{
    int tid = blockIdx.x * blockDim.x + threadIdx.x;
    int stride = gridDim.x * blockDim.x;
    for (int e = tid; e < NEDGES; e += stride) {
        atomicAdd(&cnt[ei[NEDGES + e]], 1);
    }
}

// ---------------------------------------------------------------------------
// CSR build kernel 2: exclusive scan of cnt -> rowptr (and cursor copy).
// Single block of 1024 threads; each thread owns a contiguous chunk.
// ---------------------------------------------------------------------------
__global__ __launch_bounds__(1024) void scan_kernel(
    const int* __restrict__ cnt, int* __restrict__ rowptr,
    int* __restrict__ cursor)
{
    __shared__ int part[1024];
    const int T = 1024;
    const int CH = (NNODES + T - 1) / T;   // 98
    const int t = threadIdx.x;
    const int beg = t * CH;
    const int end = (beg + CH < NNODES) ? beg + CH : NNODES;

    int s = 0;
    for (int i = beg; i < end; ++i) s += cnt[i];
    part[t] = s;
    __syncthreads();

    // Hillis-Steele inclusive scan over the 1024 partials
    for (int off = 1; off < T; off <<= 1) {
        int v = (t >= off) ? part[t - off] : 0;
        __syncthreads();
        part[t] += v;
        __syncthreads();
    }

    int run = (t == 0) ? 0 : part[t - 1];   // exclusive prefix of this chunk
    for (int i = beg; i < end; ++i) {
        rowptr[i] = run;
        cursor[i] = run;
        run += cnt[i];
    }
    if (t == T - 1) rowptr[NNODES] = run;   // == NEDGES
}

// ---------------------------------------------------------------------------
// CSR build kernel 3: scatter edge ids into per-dst slots.
// ---------------------------------------------------------------------------
__global__ __launch_bounds__(256) void fill_kernel(
    const int* __restrict__ ei, int* __restrict__ cursor,
    int* __restrict__ eid)
{
    int tid = blockIdx.x * blockDim.x + threadIdx.x;
    int stride = gridDim.x * blockDim.x;
    for (int e = tid; e < NEDGES; e += stride) {
        int dst = ei[NEDGES + e];
        int pos = atomicAdd(&cursor[dst], 1);
        eid[pos] = e;
    }
}

// ---------------------------------------------------------------------------
// Aggregation (gather): one wave per node. Sums [x[src] | edge_attr] over the
// node's in-edges in registers, writes the 640B S row exactly once. No f32
// atomics. Processes 2 edges/iter; ea reads split across wave halves.
// ---------------------------------------------------------------------------
__global__ __launch_bounds__(256) void aggregate(
    const int*   __restrict__ rowptr,
    const int*   __restrict__ eid,
    const int*   __restrict__ ei,     // [2, NEDGES]; src = ei[e]
    const float* __restrict__ x,
    const float* __restrict__ ea,
    float*       __restrict__ S)
{
    const int wave = threadIdx.x >> 6;
    const int lane = threadIdx.x & 63;
    const int n = blockIdx.x * 4 + wave;        // 100000 % 4 == 0

    const int beg = rowptr[n];
    const int end = rowptr[n + 1];

    float2 a01 = {0.f, 0.f};
    float  a2  = 0.f;

    int i = beg;
    for (; i + 2 <= end; i += 2) {
        const int e0 = eid[i];
        const int e1 = eid[i + 1];
        const int s0 = ei[e0];
        const int s1 = ei[e1];
        const float2 v0 =
            *reinterpret_cast<const float2*>(x + (size_t)s0 * HDIM + 2 * lane);
        const float2 v1 =
            *reinterpret_cast<const float2*>(x + (size_t)s1 * HDIM + 2 * lane);
        a01.x += v0.x + v1.x;
        a01.y += v0.y + v1.y;
        const int ee = (lane < 32) ? e0 : e1;   // halves cover both edges
        a2 += ea[(size_t)ee * EDIM + (lane & 31)];
    }
    if (i < end) {
        const int e0 = eid[i];
        const int s0 = ei[e0];
        const float2 v0 =
            *reinterpret_cast<const float2*>(x + (size_t)s0 * HDIM + 2 * lane);
        a01.x += v0.x;
        a01.y += v0.y;
        if (lane < 32) a2 += ea[(size_t)e0 * EDIM + lane];
    }
    a2 += __shfl_xor(a2, 32, 64);   // fold the two halves

    float* Sd = S + (size_t)n * SDIM;
    *reinterpret_cast<float2*>(Sd + 2 * lane) = a01;
    if (lane < 32) Sd[HDIM + lane] = a2;
}

// ---------------------------------------------------------------------------
// Node update: out[n] = relu(x[n]@W_self + S[n]@W_msg + b_self + deg*b_msg).
// Block = 256 threads, 64 nodes. Thread: 8 nodes x 4 cols = 32 accumulators.
// A-tile [64][288] in LDS (72KB); W read from L2 (float4, 512B/wave/instr).
// ---------------------------------------------------------------------------
__global__ __launch_bounds__(256) void node_update(
    const float* __restrict__ x,
    const float* __restrict__ S,
    const int*   __restrict__ deg,
    const float* __restrict__ Wself,  // [HDIM, HDIM]
    const float* __restrict__ bself,  // [HDIM]
    const float* __restrict__ Wmsg,   // [SDIM, HDIM]
    const float* __restrict__ bmsg,   // [HDIM]
    float*       __restrict__ out)    // [NNODES, HDIM]
{
    __shared__ float A[NT2][KTOT];    // 64 x 288 f32 = 73728 B
    __shared__ float degs[NT2];

    const int node0 = blockIdx.x * NT2;

    // stage x rows: 64 nodes x 32 float4
    for (int idx = threadIdx.x; idx < NT2 * (HDIM / 4); idx += 256) {
        const int nn = idx >> 5;
        const int k4 = idx & 31;
        float4 v = {0.f, 0.f, 0.f, 0.f};
        if (node0 + nn < NNODES)
            v = *reinterpret_cast<const float4*>(
                x + (size_t)(node0 + nn) * HDIM + k4 * 4);
        *reinterpret_cast<float4*>(&A[nn][k4 * 4]) = v;
    }
    // stage S rows: 64 nodes x 40 float4
    for (int idx = threadIdx.x; idx < NT2 * (SDIM / 4); idx += 256) {
        const int nn = idx / 40;
        const int k4 = idx - nn * 40;
        float4 v = {0.f, 0.f, 0.f, 0.f};
        if (node0 + nn < NNODES)
            v = *reinterpret_cast<const float4*>(
                S + (size_t)(node0 + nn) * SDIM + k4 * 4);
        *reinterpret_cast<float4*>(&A[nn][HDIM + k4 * 4]) = v;
    }
    if (threadIdx.x < NT2) {
        degs[threadIdx.x] = (node0 + threadIdx.x < NNODES)
                                ? (float)deg[node0 + threadIdx.x] : 0.f;
    }
    __syncthreads();

    const int tx = threadIdx.x & 31;   // col group: c0 = tx*4
    const int ty = threadIdx.x >> 5;   // node group: nodes ty*8 .. ty*8+7
    const int c0 = tx * 4;

    float acc[8][4] = {};

    // x part against W_self (k = 0..127)
    #pragma unroll 2
    for (int k = 0; k < HDIM; ++k) {
        const float4 w =
            *reinterpret_cast<const float4*>(Wself + (size_t)k * HDIM + c0);
        #pragma unroll
        for (int i = 0; i < 8; ++i) {
            const float a = A[ty * 8 + i][k];
            acc[i][0] += a * w.x; acc[i][1] += a * w.y;
            acc[i][2] += a * w.z; acc[i][3] += a * w.w;
        }
    }
    // S part against W_msg (k = 0..159)
    #pragma unroll 2
    for (int k = 0; k < SDIM; ++k) {
        const float4 w =
            *reinterpret_cast<const float4*>(Wmsg + (size_t)k * HDIM + c0);
        #pragma unroll
        for (int i = 0; i < 8; ++i) {
            const float a = A[ty * 8 + i][HDIM + k];
            acc[i][0] += a * w.x; acc[i][1] += a * w.y;
            acc[i][2] += a * w.z; acc[i][3] += a * w.w;
        }
    }

    const float4 bs = *reinterpret_cast<const float4*>(bself + c0);
    const float4 bm = *reinterpret_cast<const float4*>(bmsg + c0);

    #pragma unroll
    for (int i = 0; i < 8; ++i) {
        const int n = node0 + ty * 8 + i;
        if (n >= NNODES) continue;
        const float d = degs[ty * 8 + i];
        float4 h;
        h.x = fmaxf(acc[i][0] + bs.x + d * bm.x, 0.f);
        h.y = fmaxf(acc[i][1] + bs.y + d * bm.y, 0.f);
        h.z = fmaxf(acc[i][2] + bs.z + d * bm.z, 0.f);
        h.w = fmaxf(acc[i][3] + bs.w + d * bm.w, 0.f);
        *reinterpret_cast<float4*>(out + (size_t)n * HDIM + c0) = h;
    }
}

// ---------------------------------------------------------------------------
extern "C" void kernel_launch(void* const* d_in, const int* in_sizes, int n_in,
                              void* d_out, int out_size, void* d_ws, size_t ws_size,
                              hipStream_t stream)
{
    const float* x     = (const float*)d_in[0];
    const int*   ei    = (const int*)  d_in[1];
    const float* ea    = (const float*)d_in[2];
    const float* Wself = (const float*)d_in[3];
    const float* bself = (const float*)d_in[4];
    const float* Wmsg  = (const float*)d_in[5];
    const float* bmsg  = (const float*)d_in[6];
    float* out = (float*)d_out;

    // workspace layout (bytes):
    //   S       [NNODES*SDIM] f32      64,000,000
    //   eid     [NEDGES]      i32       6,400,000
    //   cnt     [NNODES]      i32         400,000
    //   rowptr  [NNODES+1]    i32         400,004
    //   cursor  [NNODES]      i32         400,000
    float* S      = (float*)d_ws;
    int*   eid    = (int*)(S + (size_t)NNODES * SDIM);
    int*   cnt    = eid + NEDGES;
    int*   rowptr = cnt + NNODES;
    int*   cursor = rowptr + (NNODES + 1);

    hipMemsetAsync(cnt, 0, NNODES * sizeof(int), stream);

    hist_kernel<<<2048, 256, 0, stream>>>(ei, cnt);
    scan_kernel<<<1, 1024, 0, stream>>>(cnt, rowptr, cursor);
    fill_kernel<<<2048, 256, 0, stream>>>(ei, cursor, eid);

    aggregate<<<NNODES / 4, 256, 0, stream>>>(rowptr, eid, ei, x, ea, S);

    node_update<<<(NNODES + NT2 - 1) / NT2, 256, 0, stream>>>(
        x, S, cnt /* deg == histogram counts */, Wself, bself, Wmsg, bmsg, out);
}

// Round 10
// 896.968 us; speedup vs baseline: 2.2093x; 1.2667x over previous
//
#include <hip/hip_runtime.h>

#define NNODES 100000
#define NEDGES 1600000
#define HDIM 128
#define EDIM 32
#define SDIM 160          // HDIM + EDIM
#define KTOT 288          // HDIM + SDIM (node GEMM inner dim)
#define NT2 64            // nodes per block in node kernel

// ---------------------------------------------------------------------------
// CSR build kernel 1: histogram of dst degrees.
// ---------------------------------------------------------------------------
__global__ __launch_bounds__(256) void hist_kernel(
    const int* __restrict__ ei, int* __restrict__ cnt)
{
    int tid = blockIdx.x * blockDim.x + threadIdx.x;
    int stride = gridDim.x * blockDim.x;
    for (int e = tid; e < NEDGES; e += stride) {
        atomicAdd(&cnt[ei[NEDGES + e]], 1);
    }
}

// ---------------------------------------------------------------------------
// CSR build kernel 2: exclusive scan of cnt -> rowptr (+ cursor copy).
// Single block, 1024 threads, coalesced int4 tiles + wave-shuffle scan.
// ---------------------------------------------------------------------------
__global__ __launch_bounds__(1024) void scan_kernel(
    const int* __restrict__ cnt, int* __restrict__ rowptr,
    int* __restrict__ cursor)
{
    __shared__ int warpsum[16];
    const int t = threadIdx.x;
    const int w = t >> 6;          // wave id 0..15
    const int q = t & 63;          // lane
    const int NV = NNODES / 4;     // 25000 int4 elements

    int carry = 0;
    for (int base = 0; base < NV; base += 1024) {
        const int idx = base + t;
        int4 v = {0, 0, 0, 0};
        if (idx < NV) v = reinterpret_cast<const int4*>(cnt)[idx];
        const int s = v.x + v.y + v.z + v.w;

        // inclusive wave scan of s
        int inc = s;
        #pragma unroll
        for (int off = 1; off < 64; off <<= 1) {
            int u = __shfl_up(inc, off, 64);
            if (q >= off) inc += u;
        }
        if (q == 63) warpsum[w] = inc;
        __syncthreads();
        if (w == 0) {
            int ws = (q < 16) ? warpsum[q] : 0;
            #pragma unroll
            for (int off = 1; off < 16; off <<= 1) {
                int u = __shfl_up(ws, off, 64);
                if (q >= off) ws += u;
            }
            if (q < 16) warpsum[q] = ws;   // inclusive over waves
        }
        __syncthreads();
        const int wave_prefix = (w == 0) ? 0 : warpsum[w - 1];
        const int tile_total  = warpsum[15];
        const int excl = carry + wave_prefix + (inc - s);

        int4 r;
        r.x = excl;
        r.y = r.x + v.x;
        r.z = r.y + v.y;
        r.w = r.z + v.z;
        if (idx < NV) {
            reinterpret_cast<int4*>(rowptr)[idx] = r;
            reinterpret_cast<int4*>(cursor)[idx] = r;
        }
        carry += tile_total;
        __syncthreads();   // protect warpsum before next tile
    }
    if (t == 0) rowptr[NNODES] = carry;   // == NEDGES
}

// ---------------------------------------------------------------------------
// CSR build kernel 3: scatter {src, eid} records into per-dst slots.
// ---------------------------------------------------------------------------
__global__ __launch_bounds__(256) void fill_kernel(
    const int* __restrict__ ei, int* __restrict__ cursor,
    int2* __restrict__ rec)
{
    int tid = blockIdx.x * blockDim.x + threadIdx.x;
    int stride = gridDim.x * blockDim.x;
    for (int e = tid; e < NEDGES; e += stride) {
        const int src = ei[e];
        const int dst = ei[NEDGES + e];
        const int pos = atomicAdd(&cursor[dst], 1);
        rec[pos] = make_int2(src, e);
    }
}

// ---------------------------------------------------------------------------
// Aggregation (gather): one wave per node, 4 edges per iteration.
// Lane layout: h = lane>>5 (half-wave picks edge pair), q = lane&31 covers
// the 128-float row as float4; g = lane>>4 (quarter) picks the edge whose
// 32-float ea row the 16 lanes p = lane&15 cover as float2.
// Per 4 edges: 4 uniform int2 record loads + 2 full-wave float4 x-loads
// + 1 float2 ea-load. No f32 atomics; one S-row write per node.
// ---------------------------------------------------------------------------
__global__ __launch_bounds__(256) void aggregate(
    const int*  __restrict__ rowptr,
    const int2* __restrict__ rec,
    const float* __restrict__ x,
    const float* __restrict__ ea,
    float*       __restrict__ S)
{
    const int wave = threadIdx.x >> 6;
    const int lane = threadIdx.x & 63;
    const int n = blockIdx.x * 4 + wave;        // 100000 % 4 == 0
    const int h = lane >> 5;
    const int q = lane & 31;
    const int g = lane >> 4;
    const int p = lane & 15;

    const int beg = rowptr[n];
    const int end = rowptr[n + 1];

    float4 accx = {0.f, 0.f, 0.f, 0.f};
    float2 acce = {0.f, 0.f};

    int i = beg;
    for (; i + 4 <= end; i += 4) {
        const int2 r0 = rec[i];
        const int2 r1 = rec[i + 1];
        const int2 r2 = rec[i + 2];
        const int2 r3 = rec[i + 3];

        const int sA = h ? r2.x : r0.x;
        const int sB = h ? r3.x : r1.x;
        const float4 v0 =
            *reinterpret_cast<const float4*>(x + (size_t)sA * HDIM + q * 4);
        const float4 v1 =
            *reinterpret_cast<const float4*>(x + (size_t)sB * HDIM + q * 4);

        const int eg = (g == 0) ? r0.y : (g == 1) ? r1.y
                     : (g == 2) ? r2.y : r3.y;
        const float2 wv =
            *reinterpret_cast<const float2*>(ea + (size_t)eg * EDIM + p * 2);

        accx.x += v0.x + v1.x;
        accx.y += v0.y + v1.y;
        accx.z += v0.z + v1.z;
        accx.w += v0.w + v1.w;
        acce.x += wv.x;
        acce.y += wv.y;
    }
    // tail: 0..3 edges
    for (; i < end; ++i) {
        const int2 r = rec[i];
        if (h == 0) {
            const float4 v =
                *reinterpret_cast<const float4*>(x + (size_t)r.x * HDIM + q * 4);
            accx.x += v.x; accx.y += v.y; accx.z += v.z; accx.w += v.w;
        }
        if (g == 0) {
            const float2 wv =
                *reinterpret_cast<const float2*>(ea + (size_t)r.y * EDIM + p * 2);
            acce.x += wv.x; acce.y += wv.y;
        }
    }

    // fold half-waves (x part) and quarter-groups (ea part)
    accx.x += __shfl_xor(accx.x, 32, 64);
    accx.y += __shfl_xor(accx.y, 32, 64);
    accx.z += __shfl_xor(accx.z, 32, 64);
    accx.w += __shfl_xor(accx.w, 32, 64);
    acce.x += __shfl_xor(acce.x, 32, 64);
    acce.y += __shfl_xor(acce.y, 32, 64);
    acce.x += __shfl_xor(acce.x, 16, 64);
    acce.y += __shfl_xor(acce.y, 16, 64);

    float* Sd = S + (size_t)n * SDIM;
    if (h == 0)
        *reinterpret_cast<float4*>(Sd + q * 4) = accx;
    if (g == 0)
        *reinterpret_cast<float2*>(Sd + HDIM + p * 2) = acce;
}

// ---------------------------------------------------------------------------
// Node update: out[n] = relu(x[n]@W_self + S[n]@W_msg + b_self + deg*b_msg).
// Block = 256 threads, 64 nodes. Thread: 8 nodes x 4 cols = 32 accumulators.
// A-tile [64][288] in LDS (72KB); W read from L2 (float4, 512B/wave/instr).
// ---------------------------------------------------------------------------
__global__ __launch_bounds__(256) void node_update(
    const float* __restrict__ x,
    const float* __restrict__ S,
    const int*   __restrict__ deg,
    const float* __restrict__ Wself,  // [HDIM, HDIM]
    const float* __restrict__ bself,  // [HDIM]
    const float* __restrict__ Wmsg,   // [SDIM, HDIM]
    const float* __restrict__ bmsg,   // [HDIM]
    float*       __restrict__ out)    // [NNODES, HDIM]
{
    __shared__ float A[NT2][KTOT];    // 64 x 288 f32 = 73728 B
    __shared__ float degs[NT2];

    const int node0 = blockIdx.x * NT2;

    for (int idx = threadIdx.x; idx < NT2 * (HDIM / 4); idx += 256) {
        const int nn = idx >> 5;
        const int k4 = idx & 31;
        float4 v = {0.f, 0.f, 0.f, 0.f};
        if (node0 + nn < NNODES)
            v = *reinterpret_cast<const float4*>(
                x + (size_t)(node0 + nn) * HDIM + k4 * 4);
        *reinterpret_cast<float4*>(&A[nn][k4 * 4]) = v;
    }
    for (int idx = threadIdx.x; idx < NT2 * (SDIM / 4); idx += 256) {
        const int nn = idx / 40;
        const int k4 = idx - nn * 40;
        float4 v = {0.f, 0.f, 0.f, 0.f};
        if (node0 + nn < NNODES)
            v = *reinterpret_cast<const float4*>(
                S + (size_t)(node0 + nn) * SDIM + k4 * 4);
        *reinterpret_cast<float4*>(&A[nn][HDIM + k4 * 4]) = v;
    }
    if (threadIdx.x < NT2) {
        degs[threadIdx.x] = (node0 + threadIdx.x < NNODES)
                                ? (float)deg[node0 + threadIdx.x] : 0.f;
    }
    __syncthreads();

    const int tx = threadIdx.x & 31;
    const int ty = threadIdx.x >> 5;
    const int c0 = tx * 4;

    float acc[8][4] = {};

    #pragma unroll 2
    for (int k = 0; k < HDIM; ++k) {
        const float4 w =
            *reinterpret_cast<const float4*>(Wself + (size_t)k * HDIM + c0);
        #pragma unroll
        for (int i = 0; i < 8; ++i) {
            const float a = A[ty * 8 + i][k];
            acc[i][0] += a * w.x; acc[i][1] += a * w.y;
            acc[i][2] += a * w.z; acc[i][3] += a * w.w;
        }
    }
    #pragma unroll 2
    for (int k = 0; k < SDIM; ++k) {
        const float4 w =
            *reinterpret_cast<const float4*>(Wmsg + (size_t)k * HDIM + c0);
        #pragma unroll
        for (int i = 0; i < 8; ++i) {
            const float a = A[ty * 8 + i][HDIM + k];
            acc[i][0] += a * w.x; acc[i][1] += a * w.y;
            acc[i][2] += a * w.z; acc[i][3] += a * w.w;
        }
    }

    const float4 bs = *reinterpret_cast<const float4*>(bself + c0);
    const float4 bm = *reinterpret_cast<const float4*>(bmsg + c0);

    #pragma unroll
    for (int i = 0; i < 8; ++i) {
        const int n = node0 + ty * 8 + i;
        if (n >= NNODES) continue;
        const float d = degs[ty * 8 + i];
        float4 hv;
        hv.x = fmaxf(acc[i][0] + bs.x + d * bm.x, 0.f);
        hv.y = fmaxf(acc[i][1] + bs.y + d * bm.y, 0.f);
        hv.z = fmaxf(acc[i][2] + bs.z + d * bm.z, 0.f);
        hv.w = fmaxf(acc[i][3] + bs.w + d * bm.w, 0.f);
        *reinterpret_cast<float4*>(out + (size_t)n * HDIM + c0) = hv;
    }
}

// ---------------------------------------------------------------------------
extern "C" void kernel_launch(void* const* d_in, const int* in_sizes, int n_in,
                              void* d_out, int out_size, void* d_ws, size_t ws_size,
                              hipStream_t stream)
{
    const float* x     = (const float*)d_in[0];
    const int*   ei    = (const int*)  d_in[1];
    const float* ea    = (const float*)d_in[2];
    const float* Wself = (const float*)d_in[3];
    const float* bself = (const float*)d_in[4];
    const float* Wmsg  = (const float*)d_in[5];
    const float* bmsg  = (const float*)d_in[6];
    float* out = (float*)d_out;

    // workspace layout (16B-aligned sections):
    //   S       [NNODES*SDIM] f32     64,000,000 B
    //   rec     [NEDGES]      int2    12,800,000 B
    //   cnt     [NNODES]      i32        400,000 B
    //   rowptr  [NNODES+8]    i32        400,032 B
    //   cursor  [NNODES]      i32        400,000 B
    float* S      = (float*)d_ws;
    int2*  rec    = (int2*)(S + (size_t)NNODES * SDIM);
    int*   cnt    = (int*)(rec + NEDGES);
    int*   rowptr = cnt + NNODES;
    int*   cursor = rowptr + (NNODES + 8);

    hipMemsetAsync(cnt, 0, NNODES * sizeof(int), stream);

    hist_kernel<<<2048, 256, 0, stream>>>(ei, cnt);
    scan_kernel<<<1, 1024, 0, stream>>>(cnt, rowptr, cursor);
    fill_kernel<<<2048, 256, 0, stream>>>(ei, cursor, rec);

    aggregate<<<NNODES / 4, 256, 0, stream>>>(rowptr, rec, x, ea, S);

    node_update<<<(NNODES + NT2 - 1) / NT2, 256, 0, stream>>>(
        x, S, cnt /* deg == histogram counts */, Wself, bself, Wmsg, bmsg, out);
}